// Round 4
// baseline (37504.684 us; speedup 1.0000x reference)
//
#include <hip/hip_runtime.h>
#include <cstdint>

// B=64 S=1024 D_IN=256 D_HID=512 D_LAT=128, GRU: 128->256->128, out 2
#define TOKENS 65536

// ---------------- ws layout (bytes), all f32 ----------------
// [0,64MB):    XL (65536x256)  -> reused as H0S (65536x256) after mu-GEMM
// [64,192MB):  HENC (65536x512) -> reused: GI0 half (32768x768 = 96MB) at [64,160)
// [160,192MB): Z (65536x128)
// [192MB,+1KB): MUS/MUT
#define WS_XL   0ULL
#define WS_HENC 67108864ULL
#define WS_GI0  67108864ULL
#define WS_Z    167772160ULL
#define WS_MUS  201326592ULL
#define WS_MUT  201327104ULL
#define WS_NEED 201327616ULL

// ---------------- prep: fold BN into scale/shift ----------------
__global__ void k_prep(const float* __restrict__ bmu, const float* __restrict__ bng,
                       const float* __restrict__ bnb, const float* __restrict__ bnrm,
                       const float* __restrict__ bnrv,
                       float* __restrict__ mus, float* __restrict__ mut)
{
    int j = threadIdx.x;
    if (j < 128) {
        float s = bng[j] / sqrtf(bnrv[j] + 1e-5f);
        mus[j] = s;
        mut[j] = bmu[j] * s + bnb[j] - bnrm[j] * s;
    }
}

// ---------------- xl = log(softplus(x)), f32 ----------------
__global__ void k_xl(const float* __restrict__ x, float* __restrict__ xl, int n4)
{
    int i = blockIdx.x * blockDim.x + threadIdx.x;
    if (i >= n4) return;
    float4 v = ((const float4*)x)[i];
    float4 o;
    o.x = logf(v.x > 20.f ? v.x : log1pf(expf(v.x)));
    o.y = logf(v.y > 20.f ? v.y : log1pf(expf(v.y)));
    o.z = logf(v.z > 20.f ? v.z : log1pf(expf(v.z)));
    o.w = logf(v.w > 20.f ? v.w : log1pf(expf(v.w)));
    ((float4*)xl)[i] = o;
}

// ---------------- z = mu + eps*exp(0.5*logvar), f32 ----------------
__global__ void k_z(const float* __restrict__ mu, const float* __restrict__ lv,
                    const float* __restrict__ eps, float* __restrict__ Z, int n4)
{
    int i = blockIdx.x * blockDim.x + threadIdx.x;
    if (i >= n4) return;
    float4 m = ((const float4*)mu)[i];
    float4 l = ((const float4*)lv)[i];
    float4 e = ((const float4*)eps)[i];
    float4 z;
    z.x = m.x + e.x * expf(0.5f * l.x);
    z.y = m.y + e.y * expf(0.5f * l.y);
    z.z = m.z + e.z * expf(0.5f * l.z);
    z.w = m.w + e.w * expf(0.5f * l.w);
    ((float4*)Z)[i] = z;
}

// ---------------- f32 tiled GEMM: C[m,n] = epi(acc*s[n] + t[n]) ----------------
// 128x128 tile, 256 threads, 8x8 register block. EPI: 0=none 1=relu 2=clip10 3=exp
template<int EPI>
__global__ __launch_bounds__(256) void k_gemm_f32(
    const float* __restrict__ A, const float* __restrict__ W,
    const float* __restrict__ svec, const float* __restrict__ tvec,
    float* __restrict__ C, int N, int K, int a_off)
{
    __shared__ float As[32][132];
    __shared__ float Ws[32][132];
    const int tid = threadIdx.x;
    const int tx = tid & 15, ty = tid >> 4;
    const int m0 = blockIdx.x * 128;
    const int n0 = blockIdx.y * 128;
    float acc[8][8];
#pragma unroll
    for (int i = 0; i < 8; ++i)
#pragma unroll
        for (int j = 0; j < 8; ++j) acc[i][j] = 0.f;

    for (int k0 = 0; k0 < K; k0 += 32) {
#pragma unroll
        for (int it = 0; it < 4; ++it) {
            int id = tid + 256 * it;
            int r = id >> 3, c4 = id & 7;
            float4 av = *(const float4*)(A + (size_t)(m0 + a_off + r) * K + k0 + c4 * 4);
            float4 wv = *(const float4*)(W + (size_t)(n0 + r) * K + k0 + c4 * 4);
            As[c4*4+0][r] = av.x; As[c4*4+1][r] = av.y; As[c4*4+2][r] = av.z; As[c4*4+3][r] = av.w;
            Ws[c4*4+0][r] = wv.x; Ws[c4*4+1][r] = wv.y; Ws[c4*4+2][r] = wv.z; Ws[c4*4+3][r] = wv.w;
        }
        __syncthreads();
#pragma unroll
        for (int k = 0; k < 32; ++k) {
            float4 a0 = *(const float4*)&As[k][ty*8];
            float4 a1 = *(const float4*)&As[k][ty*8+4];
            float4 w0 = *(const float4*)&Ws[k][tx*8];
            float4 w1 = *(const float4*)&Ws[k][tx*8+4];
            float ar[8] = {a0.x,a0.y,a0.z,a0.w,a1.x,a1.y,a1.z,a1.w};
            float wr[8] = {w0.x,w0.y,w0.z,w0.w,w1.x,w1.y,w1.z,w1.w};
#pragma unroll
            for (int i = 0; i < 8; ++i)
#pragma unroll
                for (int j = 0; j < 8; ++j) acc[i][j] += ar[i] * wr[j];
        }
        __syncthreads();
    }
#pragma unroll
    for (int i = 0; i < 8; ++i) {
        size_t m = (size_t)m0 + ty*8 + i;
#pragma unroll
        for (int j4 = 0; j4 < 2; ++j4) {
            float o[4];
#pragma unroll
            for (int j = 0; j < 4; ++j) {
                int col = n0 + tx*8 + j4*4 + j;
                float v = acc[i][j4*4+j];
                if (svec) v *= svec[col];
                v += tvec[col];
                if constexpr (EPI == 1) v = fmaxf(v, 0.f);
                if constexpr (EPI == 2) v = fminf(fmaxf(v, -10.f), 10.f);
                if constexpr (EPI == 3) v = expf(v);
                o[j] = v;
            }
            *(float4*)(C + m * N + n0 + tx*8 + j4*4) = *(float4*)o;
        }
    }
}

// ---------------- scan layer 0: f32; 32 blocks x 768 threads ----------------
// thread t = gate row t of Whh0: cols [0,128) in VGPRs, cols [128,256) streamed (L2).
__global__ __launch_bounds__(768) void k_scan0(
    const float* __restrict__ gi0, const float* __restrict__ wh0,
    const float* __restrict__ bhh0,
    const float* __restrict__ lg0, const float* __restrict__ lb0,
    float* __restrict__ h0s, int b_off)
{
    const int b = blockIdx.x;
    const int tid = threadIdx.x;
    const int lane = tid & 63;
    const int wv = tid >> 6;

    __shared__ float s_h[256];
    __shared__ float s_g[768];
    __shared__ float s_r1[4], s_r2[4];

    float4 wr[32];
    {
        const float4* p = (const float4*)(wh0 + (size_t)tid * 256);
#pragma unroll
        for (int i = 0; i < 32; ++i) wr[i] = p[i];
    }
    const float4* wg = (const float4*)(wh0 + (size_t)tid * 256 + 128);
    const float bA = bhh0[tid];
    float gv = 1.f, bv = 0.f, hold = 0.f;
    if (tid < 256) { gv = lg0[tid]; bv = lb0[tid]; s_h[tid] = 0.f; }
    __syncthreads();

    const float* gbase = gi0 + (size_t)b * 1024 * 768;
    float* hb = h0s + (size_t)(b + b_off) * 1024 * 256;

    for (int t = 0; t < 1024; ++t) {
        const float* gt = gbase + (size_t)t * 768;
        float gr = 0.f, gz = 0.f, gn = 0.f;
        if (tid < 256) { gr = gt[tid]; gz = gt[tid + 256]; gn = gt[tid + 512]; }
        float a0 = bA, a1 = 0.f, a2 = 0.f, a3 = 0.f;
        const float4* H = (const float4*)s_h;
#pragma unroll
        for (int i = 0; i < 32; ++i) {
            float4 h4 = H[i];
            a0 += wr[i].x * h4.x; a1 += wr[i].y * h4.y;
            a2 += wr[i].z * h4.z; a3 += wr[i].w * h4.w;
        }
#pragma unroll 8
        for (int i = 0; i < 32; ++i) {
            float4 w4 = wg[i];
            float4 h4 = H[32 + i];
            a0 += w4.x * h4.x; a1 += w4.y * h4.y;
            a2 += w4.z * h4.z; a3 += w4.w * h4.w;
        }
        s_g[tid] = (a0 + a1) + (a2 + a3);
        __syncthreads();
        // gates + mean-reduction
        float hn = 0.f;
        if (tid < 256) {
            float r  = 1.f / (1.f + expf(-(gr + s_g[tid])));
            float zg = 1.f / (1.f + expf(-(gz + s_g[tid + 256])));
            float nn = tanhf(gn + r * s_g[tid + 512]);
            hn = (1.f - zg) * nn + zg * hold;
            float sum = hn;
#pragma unroll
            for (int o = 32; o > 0; o >>= 1) sum += __shfl_xor(sum, o);
            if (lane == 0) s_r1[wv] = sum;
        }
        __syncthreads();
        // two-pass variance
        float d = 0.f;
        if (tid < 256) {
            float m = (s_r1[0] + s_r1[1] + s_r1[2] + s_r1[3]) * (1.f / 256.f);
            d = hn - m;
            float ss = d * d;
#pragma unroll
            for (int o = 32; o > 0; o >>= 1) ss += __shfl_xor(ss, o);
            if (lane == 0) s_r2[wv] = ss;
        }
        __syncthreads();
        if (tid < 256) {
            float va = (s_r2[0] + s_r2[1] + s_r2[2] + s_r2[3]) * (1.f / 256.f);
            float rs = 1.f / sqrtf(va + 1e-5f);
            float hl = d * rs * gv + bv;
            hold = hl;
            s_h[tid] = hl;
            hb[(size_t)t * 256 + tid] = hl;
        }
        __syncthreads();
    }
}

// ---------------- scan layer 1: f32; 64 blocks x 768 threads ----------------
// tid<384: Wih1 row tid (cols[0,128) regs, [128,256) streamed); tid>=384: Whh1 row (128, all regs)
__global__ __launch_bounds__(768) void k_scan1(
    const float* __restrict__ h0s, const float* __restrict__ wi1, const float* __restrict__ wh1,
    const float* __restrict__ bih1, const float* __restrict__ bhh1,
    const float* __restrict__ lg1, const float* __restrict__ lb1,
    const float* __restrict__ fcW, const float* __restrict__ fcb,
    float* __restrict__ vout)
{
    const int b = blockIdx.x;
    const int tid = threadIdx.x;
    const int lane = tid & 63;
    const int wv = tid >> 6;

    __shared__ float s_x[256];
    __shared__ float s_h[128];
    __shared__ float s_g[768];
    __shared__ float s_r1[2], s_r2[2];

    float4 wr[32];
    const float4* wg = nullptr;
    float bB;
    if (tid < 384) {
        const float4* p = (const float4*)(wi1 + (size_t)tid * 256);
#pragma unroll
        for (int i = 0; i < 32; ++i) wr[i] = p[i];
        wg = p + 32;
        bB = bih1[tid];
    } else {
        const float4* p = (const float4*)(wh1 + (size_t)(tid - 384) * 128);
#pragma unroll
        for (int i = 0; i < 32; ++i) wr[i] = p[i];
        bB = bhh1[tid - 384];
    }
    float gv = 1.f, bv = 0.f, hold = 0.f;
    if (tid < 128) { gv = lg1[tid]; bv = lb1[tid]; s_h[tid] = 0.f; }
    __syncthreads();

    const float4* xb = (const float4*)(h0s + (size_t)b * 1024 * 256);

    for (int t = 0; t < 1024; ++t) {
        if (tid < 64) ((float4*)s_x)[tid] = xb[(size_t)t * 64 + tid];
        __syncthreads();
        float a0 = bB, a1 = 0.f, a2 = 0.f, a3 = 0.f;
        if (tid < 384) {
            const float4* X = (const float4*)s_x;
#pragma unroll
            for (int i = 0; i < 32; ++i) {
                float4 h4 = X[i];
                a0 += wr[i].x * h4.x; a1 += wr[i].y * h4.y;
                a2 += wr[i].z * h4.z; a3 += wr[i].w * h4.w;
            }
#pragma unroll 8
            for (int i = 0; i < 32; ++i) {
                float4 w4 = wg[i];
                float4 h4 = X[32 + i];
                a0 += w4.x * h4.x; a1 += w4.y * h4.y;
                a2 += w4.z * h4.z; a3 += w4.w * h4.w;
            }
        } else {
            const float4* Hh = (const float4*)s_h;
#pragma unroll
            for (int i = 0; i < 32; ++i) {
                float4 h4 = Hh[i];
                a0 += wr[i].x * h4.x; a1 += wr[i].y * h4.y;
                a2 += wr[i].z * h4.z; a3 += wr[i].w * h4.w;
            }
        }
        s_g[tid] = (a0 + a1) + (a2 + a3);
        __syncthreads();
        float hn = 0.f;
        if (tid < 128) {
            float r  = 1.f / (1.f + expf(-(s_g[tid]       + s_g[384 + tid])));
            float zg = 1.f / (1.f + expf(-(s_g[128 + tid] + s_g[512 + tid])));
            float nn = tanhf(s_g[256 + tid] + r * s_g[640 + tid]);
            hn = (1.f - zg) * nn + zg * hold;
            float sum = hn;
#pragma unroll
            for (int o = 32; o > 0; o >>= 1) sum += __shfl_xor(sum, o);
            if (lane == 0) s_r1[wv] = sum;
        }
        __syncthreads();
        float d = 0.f;
        if (tid < 128) {
            float m = (s_r1[0] + s_r1[1]) * (1.f / 128.f);
            d = hn - m;
            float ss = d * d;
#pragma unroll
            for (int o = 32; o > 0; o >>= 1) ss += __shfl_xor(ss, o);
            if (lane == 0) s_r2[wv] = ss;
        }
        __syncthreads();
        if (tid < 128) {
            float va = (s_r2[0] + s_r2[1]) * (1.f / 128.f);
            float rs = 1.f / sqrtf(va + 1e-5f);
            float hl = d * rs * gv + bv;
            hold = hl;
            s_h[tid] = hl;
        }
        __syncthreads();
    }
    float p0 = 0.f, p1 = 0.f;
    if (tid < 128) {
        p0 = fcW[tid] * hold;
        p1 = fcW[128 + tid] * hold;
#pragma unroll
        for (int o = 32; o > 0; o >>= 1) { p0 += __shfl_xor(p0, o); p1 += __shfl_xor(p1, o); }
        if (lane == 0) { s_r1[wv] = p0; s_r2[wv] = p1; }
    }
    __syncthreads();
    if (tid == 0) {
        vout[b * 2 + 0] = s_r1[0] + s_r1[1] + fcb[0];
        vout[b * 2 + 1] = s_r2[0] + s_r2[1] + fcb[1];
    }
}

// ---------------- launcher ----------------
extern "C" void kernel_launch(void* const* d_in, const int* in_sizes, int n_in,
                              void* d_out, int out_size, void* d_ws, size_t ws_size,
                              hipStream_t stream)
{
    const float* x     = (const float*)d_in[0];
    const float* eps   = (const float*)d_in[1];
    const float* W1lv  = (const float*)d_in[2];
    const float* b1lv  = (const float*)d_in[3];
    const float* W2lv  = (const float*)d_in[4];
    const float* b2lv  = (const float*)d_in[5];
    const float* Wmu   = (const float*)d_in[6];
    const float* bmu   = (const float*)d_in[7];
    const float* bn_g  = (const float*)d_in[8];
    const float* bn_b  = (const float*)d_in[9];
    const float* bn_rm = (const float*)d_in[10];
    const float* bn_rv = (const float*)d_in[11];
    const float* Wdec  = (const float*)d_in[12];
    const float* bdec  = (const float*)d_in[13];
    const float* Wih0  = (const float*)d_in[14];
    const float* Whh0  = (const float*)d_in[15];
    const float* bih0  = (const float*)d_in[16];
    const float* bhh0  = (const float*)d_in[17];
    const float* Wih1  = (const float*)d_in[18];
    const float* Whh1  = (const float*)d_in[19];
    const float* bih1  = (const float*)d_in[20];
    const float* bhh1  = (const float*)d_in[21];
    const float* ln_g0 = (const float*)d_in[22];
    const float* ln_b0 = (const float*)d_in[23];
    const float* ln_g1 = (const float*)d_in[24];
    const float* ln_b1 = (const float*)d_in[25];
    const float* fc_W  = (const float*)d_in[26];
    const float* fc_b  = (const float*)d_in[27];

    float* out   = (float*)d_out;
    float* v_out = out;                                   // [64,2]
    float* xrec  = out + 128;                             // [64,1024,256]
    float* mu    = out + 128 + 16777216;                  // [64,1024,128]
    float* lv    = out + 128 + 16777216 + 8388608;        // [64,1024,128]

    if (ws_size < WS_NEED) return;  // distinctive failure: outputs stay zero
    char* ws = (char*)d_ws;
    float* XL   = (float*)(ws + WS_XL);
    float* H0S  = (float*)(ws + WS_XL);    // overlays XL (dead after mu-GEMM)
    float* HENC = (float*)(ws + WS_HENC);
    float* GI0h = (float*)(ws + WS_GI0);   // 96MB half (overlays dead HENC)
    float* Z    = (float*)(ws + WS_Z);
    float* MUS  = (float*)(ws + WS_MUS);
    float* MUT  = (float*)(ws + WS_MUT);

    k_prep<<<1, 128, 0, stream>>>(bmu, bn_g, bn_b, bn_rm, bn_rv, MUS, MUT);
    k_xl<<<16384, 256, 0, stream>>>(x, XL, 4194304);
    // encoder
    k_gemm_f32<1><<<dim3(512, 4), 256, 0, stream>>>(XL,   W1lv, nullptr, b1lv, HENC, 512, 256, 0);
    k_gemm_f32<0><<<dim3(512, 1), 256, 0, stream>>>(HENC, W2lv, nullptr, b2lv, lv,   128, 512, 0);
    k_gemm_f32<2><<<dim3(512, 1), 256, 0, stream>>>(XL,   Wmu,  MUS,     MUT,  mu,   128, 256, 0);
    // reparameterize
    k_z<<<8192, 256, 0, stream>>>(mu, lv, eps, Z, 2097152);
    // decoder
    k_gemm_f32<3><<<dim3(512, 2), 256, 0, stream>>>(Z, Wdec, nullptr, bdec, xrec, 256, 128, 0);
    // gi0 + scan layer 0, in two batch halves (GI0 f32 = 192MB doesn't fit ws whole)
    k_gemm_f32<0><<<dim3(256, 6), 256, 0, stream>>>(Z, Wih0, nullptr, bih0, GI0h, 768, 128, 0);
    k_scan0<<<32, 768, 0, stream>>>(GI0h, Whh0, bhh0, ln_g0, ln_b0, H0S, 0);
    k_gemm_f32<0><<<dim3(256, 6), 256, 0, stream>>>(Z, Wih0, nullptr, bih0, GI0h, 768, 128, 32768);
    k_scan0<<<32, 768, 0, stream>>>(GI0h, Whh0, bhh0, ln_g0, ln_b0, H0S, 32);
    // scan layer 1 + fc head
    k_scan1<<<64, 768, 0, stream>>>(H0S, Wih1, Whh1, bih1, bhh1, ln_g1, ln_b1, fc_W, fc_b, v_out);
}